// Round 1
// baseline (255.905 us; speedup 1.0000x reference)
//
#include <hip/hip_runtime.h>
#include <math.h>

// Problem constants (SimpleVQ): B=32, H=1, L=4096, D=64, S=512
#define NB 32
#define NL 4096
#define ND 64
#define NS 512
#define NTOK (NB * NL)          // 131072 tokens
#define BLOCK 256
#define NBLK (NTOK / BLOCK)     // 512 blocks

// Output layout (flat f32, reference return order):
//   quantized [B,1,L,D] : NTOK*ND        = 8388608
//   z         [B,1,L]   : NTOK           = 131072
//   l_commit  scalar    : 1
//   errs2     [B,1,L]   : NTOK           = 131072
#define OFF_Q 0
#define OFF_Z (NTOK * ND)
#define OFF_LC (OFF_Z + NTOK)
#define OFF_E (OFF_LC + 1)

// ---------------------------------------------------------------------------
// Kernel 1: build codebook [S][D] and per-code squared norms cc[S] in ws.
// Sinusoid table -> rms-norm -> * tau^{-1/2}.  Double-precision transcendental
// evaluation to track the numpy reference as closely as possible.
// ---------------------------------------------------------------------------
__global__ void cb_kernel(float* __restrict__ cb, float* __restrict__ cc) {
    int s = blockIdx.x;        // code position 0..511
    int d = threadIdx.x;       // dim 0..63
    int j = (d < 32) ? d : (d - 32);
    double e = -(double)(2 * j) / 64.0;
    double invlam = pow(100000.0, e);        // lam^{-2j/D}
    double pre = (double)s * invlam;
    float val = (float)((d < 32) ? sin(pre) : cos(pre));

    // wave(64)-wide reduce of val^2 for rms-norm
    float sq = val * val;
    #pragma unroll
    for (int off = 32; off > 0; off >>= 1) sq += __shfl_xor(sq, off);
    float mean = sq * (1.0f / 64.0f);
    float scale = (1.0f / sqrtf(mean + 1e-6f)) * 0.35355339059327379f; // * 8^{-1/2}
    float c = val * scale;
    cb[s * ND + d] = c;

    // cc[s] = sum_d c^2 (as computed on the stored f32 values)
    float c2 = c * c;
    #pragma unroll
    for (int off = 32; off > 0; off >>= 1) c2 += __shfl_xor(c2, off);
    if (d == 0) cc[s] = c2;
}

// ---------------------------------------------------------------------------
// Kernel 2: one token per thread. v[64] in VGPRs; codebook read with uniform
// addresses (scalar loads, SMEM pipe) -> VALU does almost pure FMA.
// ---------------------------------------------------------------------------
__launch_bounds__(BLOCK, 2)
__global__ void vq_kernel(const float* __restrict__ vecs,
                          const float* __restrict__ mask,
                          const float* __restrict__ cb,
                          const float* __restrict__ cc,
                          float* __restrict__ outq,
                          float* __restrict__ outz,
                          float* __restrict__ oute,
                          float* __restrict__ partial) {
    const int tok = blockIdx.x * BLOCK + threadIdx.x;

    // load this token's vector (16 x float4, contiguous 256B per thread)
    float v[ND];
    {
        const float4* vr = (const float4*)(vecs + (size_t)tok * ND);
        #pragma unroll
        for (int i = 0; i < ND / 4; ++i) {
            float4 t = vr[i];
            v[4 * i + 0] = t.x; v[4 * i + 1] = t.y;
            v[4 * i + 2] = t.z; v[4 * i + 3] = t.w;
        }
    }

    // ||v||^2 with 4 independent accumulation chains
    float vv;
    {
        float a0 = 0.f, a1 = 0.f, a2 = 0.f, a3 = 0.f;
        #pragma unroll
        for (int k = 0; k < ND; k += 4) {
            a0 = fmaf(v[k + 0], v[k + 0], a0);
            a1 = fmaf(v[k + 1], v[k + 1], a1);
            a2 = fmaf(v[k + 2], v[k + 2], a2);
            a3 = fmaf(v[k + 3], v[k + 3], a3);
        }
        vv = (a0 + a1) + (a2 + a3);
    }

    float best = 3.4e38f;
    int bidx = 0;
    for (int s = 0; s < NS; ++s) {
        const float* cs = cb + s * ND;   // uniform address -> s_load
        float d0 = 0.f, d1 = 0.f, d2 = 0.f, d3 = 0.f;
        #pragma unroll
        for (int k = 0; k < ND; k += 4) {
            d0 = fmaf(cs[k + 0], v[k + 0], d0);
            d1 = fmaf(cs[k + 1], v[k + 1], d1);
            d2 = fmaf(cs[k + 2], v[k + 2], d2);
            d3 = fmaf(cs[k + 3], v[k + 3], d3);
        }
        float dot = (d0 + d1) + (d2 + d3);
        float dist = (vv - 2.0f * dot) + cc[s];  // reference formula/order
        if (dist < best) { best = dist; bidx = s; }  // strict '<': first min, jnp.argmin parity
    }

    float err = fmaxf(best, 0.0f);       // relu(min)
    outz[tok] = (float)bidx;
    oute[tok] = err;

    // quantized = c[z] exactly (vecs - stop_grad(vecs) == 0)
    {
        const float4* cz = (const float4*)(cb + (size_t)bidx * ND);
        float4* qo = (float4*)(outq + (size_t)tok * ND);
        #pragma unroll
        for (int i = 0; i < ND / 4; ++i) qo[i] = cz[i];
    }

    // deterministic per-block partial of mask*errs2
    float contrib = mask[tok] * err;
    #pragma unroll
    for (int off = 32; off > 0; off >>= 1) contrib += __shfl_xor(contrib, off);
    __shared__ float wsum[BLOCK / 64];
    const int wid = threadIdx.x >> 6;
    if ((threadIdx.x & 63) == 0) wsum[wid] = contrib;
    __syncthreads();
    if (threadIdx.x == 0) {
        float t = 0.f;
        #pragma unroll
        for (int i = 0; i < BLOCK / 64; ++i) t += wsum[i];
        partial[blockIdx.x] = t;
    }
}

// ---------------------------------------------------------------------------
// Kernel 3: sum the 512 block partials deterministically; l_commit = sum/(B*L)
// ---------------------------------------------------------------------------
__global__ void fin_kernel(const float* __restrict__ partial, float* __restrict__ outl) {
    int t = threadIdx.x;                 // 512 threads
    float x = (t < NBLK) ? partial[t] : 0.0f;
    #pragma unroll
    for (int off = 32; off > 0; off >>= 1) x += __shfl_xor(x, off);
    __shared__ float ws[8];
    if ((t & 63) == 0) ws[t >> 6] = x;
    __syncthreads();
    if (t == 0) {
        float s = 0.f;
        #pragma unroll
        for (int i = 0; i < 8; ++i) s += ws[i];
        outl[0] = s / (float)NTOK;
    }
}

extern "C" void kernel_launch(void* const* d_in, const int* in_sizes, int n_in,
                              void* d_out, int out_size, void* d_ws, size_t ws_size,
                              hipStream_t stream) {
    const float* vecs = (const float*)d_in[0];   // [B,1,L,D] f32
    const float* mask = (const float*)d_in[1];   // [B,L] f32

    float* out = (float*)d_out;
    float* outq = out + OFF_Q;
    float* outz = out + OFF_Z;
    float* outl = out + OFF_LC;
    float* oute = out + OFF_E;

    float* cb = (float*)d_ws;            // [S*D] = 32768 f32
    float* cc = cb + NS * ND;            // [S]
    float* partial = cc + NS;            // [NBLK]

    cb_kernel<<<NS, 64, 0, stream>>>(cb, cc);
    vq_kernel<<<NBLK, BLOCK, 0, stream>>>(vecs, mask, cb, cc,
                                          outq, outz, oute, partial);
    fin_kernel<<<1, 512, 0, stream>>>(partial, outl);
}

// Round 2
// 149.708 us; speedup vs baseline: 1.7094x; 1.7094x over previous
//
#include <hip/hip_runtime.h>
#include <math.h>

// Problem constants (SimpleVQ): B=32, H=1, L=4096, D=64, S=512
#define NB 32
#define NL 4096
#define ND 64
#define NS 512
#define NTOK (NB * NL)            // 131072 tokens

#define TPB 256                   // threads per block
#define TOKS_PER_BLK 64           // tokens per block
#define NCHUNK 4                  // code chunks per block (TPB/TOKS_PER_BLK)
#define CODES_PER_CHUNK (NS / NCHUNK)   // 128
#define NBLK (NTOK / TOKS_PER_BLK)      // 2048 blocks

// Output layout (flat f32, reference return order):
#define OFF_Q 0
#define OFF_Z (NTOK * ND)
#define OFF_LC (OFF_Z + NTOK)
#define OFF_E (OFF_LC + 1)

// ---------------------------------------------------------------------------
// Kernel 1: build codebook [S][D] and per-code squared norms cc[S] in ws.
// ---------------------------------------------------------------------------
__global__ void cb_kernel(float* __restrict__ cb, float* __restrict__ cc) {
    int s = blockIdx.x;        // code position 0..511
    int d = threadIdx.x;       // dim 0..63
    int j = (d < 32) ? d : (d - 32);
    double e = -(double)(2 * j) / 64.0;
    double invlam = pow(100000.0, e);        // lam^{-2j/D}
    double pre = (double)s * invlam;
    float val = (float)((d < 32) ? sin(pre) : cos(pre));

    float sq = val * val;
    #pragma unroll
    for (int off = 32; off > 0; off >>= 1) sq += __shfl_xor(sq, off);
    float mean = sq * (1.0f / 64.0f);
    float scale = (1.0f / sqrtf(mean + 1e-6f)) * 0.35355339059327379f; // * 8^{-1/2}
    float c = val * scale;
    cb[s * ND + d] = c;

    float c2 = c * c;
    #pragma unroll
    for (int off = 32; off > 0; off >>= 1) c2 += __shfl_xor(c2, off);
    if (d == 0) cc[s] = c2;
}

// ---------------------------------------------------------------------------
// Kernel 2: 64 tokens x 4 code-chunks per block. Each thread: 1 token vs 128
// codes, v in VGPRs, codebook via wave-uniform scalar loads. Chunk argmins
// combined through LDS with packed (dist,idx) keys -> exact first-min
// semantics. Coalesced gather-write of quantized.
// ---------------------------------------------------------------------------
__global__ void vq_kernel(const float* __restrict__ vecs,
                          const float* __restrict__ mask,
                          const float* __restrict__ cb,
                          const float* __restrict__ cc,
                          float* __restrict__ outq,
                          float* __restrict__ outz,
                          float* __restrict__ oute,
                          float* __restrict__ partial) {
    const int tid = threadIdx.x;
    const int tl  = tid & (TOKS_PER_BLK - 1);                 // token-local 0..63
    const int chunk = __builtin_amdgcn_readfirstlane(tid >> 6); // wave-uniform 0..3
    const int tok = blockIdx.x * TOKS_PER_BLK + tl;

    // token vector -> 16 float4 in VGPRs
    float4 vf[ND / 4];
    {
        const float4* vr = (const float4*)(vecs + (size_t)tok * ND);
        #pragma unroll
        for (int i = 0; i < ND / 4; ++i) vf[i] = vr[i];
    }

    // ||v||^2, 4 independent chains (x,y,z,w) — same order as round 0
    float vv;
    {
        float a0 = 0.f, a1 = 0.f, a2 = 0.f, a3 = 0.f;
        #pragma unroll
        for (int i = 0; i < ND / 4; ++i) {
            a0 = fmaf(vf[i].x, vf[i].x, a0);
            a1 = fmaf(vf[i].y, vf[i].y, a1);
            a2 = fmaf(vf[i].z, vf[i].z, a2);
            a3 = fmaf(vf[i].w, vf[i].w, a3);
        }
        vv = (a0 + a1) + (a2 + a3);
    }

    // scan this chunk's 128 codes
    const int cbase = chunk * CODES_PER_CHUNK;
    const float* cbc = cb + (size_t)cbase * ND;   // wave-uniform base
    const float* ccc = cc + cbase;

    float best = 3.4e38f;
    int bidx = 0;
    for (int s = 0; s < CODES_PER_CHUNK; ++s) {
        const float4* cs = (const float4*)(cbc + (size_t)s * ND); // uniform -> s_load
        float d0 = 0.f, d1 = 0.f, d2 = 0.f, d3 = 0.f;
        #pragma unroll
        for (int i = 0; i < ND / 4; ++i) {
            float4 cv = cs[i];
            d0 = fmaf(cv.x, vf[i].x, d0);
            d1 = fmaf(cv.y, vf[i].y, d1);
            d2 = fmaf(cv.z, vf[i].z, d2);
            d3 = fmaf(cv.w, vf[i].w, d3);
        }
        float dot = (d0 + d1) + (d2 + d3);
        float dist = (vv - 2.0f * dot) + ccc[s];   // reference order
        if (dist < best) { best = dist; bidx = cbase + s; }  // strict '<'
    }

    // pack (dist,idx) into an order-preserving uint64 key
    unsigned int u = __float_as_uint(best);
    u ^= (u >> 31) ? 0xFFFFFFFFu : 0x80000000u;   // monotone map f32 -> u32
    unsigned long long key = ((unsigned long long)u << 32) | (unsigned int)bidx;

    __shared__ unsigned long long keys[NCHUNK][TOKS_PER_BLK];
    __shared__ int z_l[TOKS_PER_BLK];
    __shared__ float wsum[TPB / 64];
    keys[chunk][tl] = key;
    __syncthreads();

    // threads 0..63 combine the 4 chunks; min key == min dist, smaller idx on tie
    float contrib = 0.0f;
    if (tid < TOKS_PER_BLK) {
        unsigned long long k = keys[0][tid];
        #pragma unroll
        for (int c = 1; c < NCHUNK; ++c) {
            unsigned long long kc = keys[c][tid];
            if (kc < k) k = kc;
        }
        int zi = (int)(k & 0xFFFFFFFFu);
        unsigned int du = (unsigned int)(k >> 32);
        du ^= (du >> 31) ? 0x80000000u : 0xFFFFFFFFu;  // decode
        float dmin = __uint_as_float(du);
        float err = fmaxf(dmin, 0.0f);
        outz[tok] = (float)zi;
        oute[tok] = err;
        z_l[tid] = zi;
        contrib = mask[tok] * err;
    }

    // block partial of mask*errs2 (deterministic)
    #pragma unroll
    for (int off = 32; off > 0; off >>= 1) contrib += __shfl_xor(contrib, off);
    if ((tid & 63) == 0) wsum[tid >> 6] = contrib;
    __syncthreads();
    if (tid == 0) {
        float t = 0.f;
        #pragma unroll
        for (int i = 0; i < TPB / 64; ++i) t += wsum[i];
        partial[blockIdx.x] = t;
    }

    // coalesced quantized gather-write: block's 64 tokens * 64 floats = 1024 float4
    float4* qo = (float4*)(outq + (size_t)blockIdx.x * TOKS_PER_BLK * ND);
    const float4* cb4 = (const float4*)cb;
    #pragma unroll
    for (int i = 0; i < (TOKS_PER_BLK * ND / 4) / TPB; ++i) {  // 4 iters
        int g = i * TPB + tid;        // float4 index within block region
        int t = g >> 4;               // local token
        int sub = g & 15;
        int zi = z_l[t];
        qo[g] = cb4[(size_t)zi * 16 + sub];
    }
}

// ---------------------------------------------------------------------------
// Kernel 3: sum 2048 block partials deterministically; l_commit = sum/(B*L)
// ---------------------------------------------------------------------------
__global__ void fin_kernel(const float* __restrict__ partial, float* __restrict__ outl) {
    int t = threadIdx.x;                 // 1024 threads
    float x = partial[t] + partial[t + 1024];
    #pragma unroll
    for (int off = 32; off > 0; off >>= 1) x += __shfl_xor(x, off);
    __shared__ float ws[16];
    if ((t & 63) == 0) ws[t >> 6] = x;
    __syncthreads();
    if (t == 0) {
        float s = 0.f;
        #pragma unroll
        for (int i = 0; i < 16; ++i) s += ws[i];
        outl[0] = s / (float)NTOK;
    }
}

extern "C" void kernel_launch(void* const* d_in, const int* in_sizes, int n_in,
                              void* d_out, int out_size, void* d_ws, size_t ws_size,
                              hipStream_t stream) {
    const float* vecs = (const float*)d_in[0];   // [B,1,L,D] f32
    const float* mask = (const float*)d_in[1];   // [B,L] f32

    float* out = (float*)d_out;
    float* outq = out + OFF_Q;
    float* outz = out + OFF_Z;
    float* outl = out + OFF_LC;
    float* oute = out + OFF_E;

    float* cb = (float*)d_ws;            // [S*D] = 32768 f32
    float* cc = cb + NS * ND;            // [S]
    float* partial = cc + NS;            // [NBLK] = 2048

    cb_kernel<<<NS, 64, 0, stream>>>(cb, cc);
    vq_kernel<<<NBLK, TPB, 0, stream>>>(vecs, mask, cb, cc,
                                        outq, outz, oute, partial);
    fin_kernel<<<1, 1024, 0, stream>>>(partial, outl);
}

// Round 3
// 148.256 us; speedup vs baseline: 1.7261x; 1.0098x over previous
//
#include <hip/hip_runtime.h>
#include <math.h>

// Problem constants (SimpleVQ): B=32, H=1, L=4096, D=64, S=512
#define NB 32
#define NL 4096
#define ND 64
#define NS 512
#define NTOK (NB * NL)            // 131072 tokens

#define TPB 256                   // threads per block
#define TOKS_PER_BLK 64           // tokens per block
#define NCHUNK 4                  // code chunks per block (TPB/TOKS_PER_BLK)
#define CODES_PER_CHUNK (NS / NCHUNK)   // 128
#define NBLK (NTOK / TOKS_PER_BLK)      // 2048 blocks

// Output layout (flat f32, reference return order):
#define OFF_Q 0
#define OFF_Z (NTOK * ND)
#define OFF_LC (OFF_Z + NTOK)
#define OFF_E (OFF_LC + 1)

// ---------------------------------------------------------------------------
// Kernel 1: build codebook [S][D] and per-code squared norms cc[S] in ws.
// ---------------------------------------------------------------------------
__global__ void cb_kernel(float* __restrict__ cb, float* __restrict__ cc) {
    int s = blockIdx.x;        // code position 0..511
    int d = threadIdx.x;       // dim 0..63
    int j = (d < 32) ? d : (d - 32);
    double e = -(double)(2 * j) / 64.0;
    double invlam = pow(100000.0, e);        // lam^{-2j/D}
    double pre = (double)s * invlam;
    float val = (float)((d < 32) ? sin(pre) : cos(pre));

    float sq = val * val;
    #pragma unroll
    for (int off = 32; off > 0; off >>= 1) sq += __shfl_xor(sq, off);
    float mean = sq * (1.0f / 64.0f);
    float scale = (1.0f / sqrtf(mean + 1e-6f)) * 0.35355339059327379f; // * 8^{-1/2}
    float c = val * scale;
    cb[s * ND + d] = c;

    float c2 = c * c;
    #pragma unroll
    for (int off = 32; off > 0; off >>= 1) c2 += __shfl_xor(c2, off);
    if (d == 0) cc[s] = c2;
}

// ---------------------------------------------------------------------------
// Kernel 2: 64 tokens x 4 code-chunks per block. Each thread: 1 token vs 128
// codes. Token vector PINNED in VGPRs (asm "+v") so the compiler cannot
// rematerialize the global loads inside the code loop; codebook read via
// wave-uniform scalar loads. Chunk argmins combined through LDS with packed
// (dist,idx) keys -> exact first-min semantics. Coalesced gather-write.
// ---------------------------------------------------------------------------
__launch_bounds__(TPB, 4)
__global__ void vq_kernel(const float* __restrict__ vecs,
                          const float* __restrict__ mask,
                          const float* __restrict__ cb,
                          const float* __restrict__ cc,
                          float* __restrict__ outq,
                          float* __restrict__ outz,
                          float* __restrict__ oute,
                          float* __restrict__ partial) {
    const int tid = threadIdx.x;
    const int tl  = tid & (TOKS_PER_BLK - 1);                 // token-local 0..63
    const int chunk = __builtin_amdgcn_readfirstlane(tid >> 6); // wave-uniform 0..3
    const int tok = blockIdx.x * TOKS_PER_BLK + tl;

    // token vector -> 16 float4 in VGPRs, then pin (non-rematerializable)
    float4 vf[ND / 4];
    {
        const float4* vr = (const float4*)(vecs + (size_t)tok * ND);
        #pragma unroll
        for (int i = 0; i < ND / 4; ++i) vf[i] = vr[i];
    }
    #pragma unroll
    for (int i = 0; i < ND / 4; ++i) {
        asm volatile("" : "+v"(vf[i].x), "+v"(vf[i].y), "+v"(vf[i].z), "+v"(vf[i].w));
    }

    // ||v||^2, 4 independent chains (x,y,z,w) — same order as rounds 0-2
    float vv;
    {
        float a0 = 0.f, a1 = 0.f, a2 = 0.f, a3 = 0.f;
        #pragma unroll
        for (int i = 0; i < ND / 4; ++i) {
            a0 = fmaf(vf[i].x, vf[i].x, a0);
            a1 = fmaf(vf[i].y, vf[i].y, a1);
            a2 = fmaf(vf[i].z, vf[i].z, a2);
            a3 = fmaf(vf[i].w, vf[i].w, a3);
        }
        vv = (a0 + a1) + (a2 + a3);
    }

    // scan this chunk's 128 codes
    const int cbase = chunk * CODES_PER_CHUNK;
    const float* cbc = cb + (size_t)cbase * ND;   // wave-uniform base
    const float* ccc = cc + cbase;

    float best = 3.4e38f;
    int bidx = 0;
    for (int s = 0; s < CODES_PER_CHUNK; ++s) {
        const float4* cs = (const float4*)(cbc + (size_t)s * ND); // uniform -> s_load
        float d0 = 0.f, d1 = 0.f, d2 = 0.f, d3 = 0.f;
        #pragma unroll
        for (int i = 0; i < ND / 4; ++i) {
            float4 cv = cs[i];
            d0 = fmaf(cv.x, vf[i].x, d0);
            d1 = fmaf(cv.y, vf[i].y, d1);
            d2 = fmaf(cv.z, vf[i].z, d2);
            d3 = fmaf(cv.w, vf[i].w, d3);
        }
        float dot = (d0 + d1) + (d2 + d3);
        float dist = (vv - 2.0f * dot) + ccc[s];   // reference order
        if (dist < best) { best = dist; bidx = cbase + s; }  // strict '<'
    }

    // pack (dist,idx) into an order-preserving uint64 key
    unsigned int u = __float_as_uint(best);
    u ^= (u >> 31) ? 0xFFFFFFFFu : 0x80000000u;   // monotone map f32 -> u32
    unsigned long long key = ((unsigned long long)u << 32) | (unsigned int)bidx;

    __shared__ unsigned long long keys[NCHUNK][TOKS_PER_BLK];
    __shared__ int z_l[TOKS_PER_BLK];
    __shared__ float wsum[TPB / 64];
    keys[chunk][tl] = key;
    __syncthreads();

    // threads 0..63 combine the 4 chunks; min key == min dist, smaller idx on tie
    float contrib = 0.0f;
    if (tid < TOKS_PER_BLK) {
        unsigned long long k = keys[0][tid];
        #pragma unroll
        for (int c = 1; c < NCHUNK; ++c) {
            unsigned long long kc = keys[c][tid];
            if (kc < k) k = kc;
        }
        int zi = (int)(k & 0xFFFFFFFFu);
        unsigned int du = (unsigned int)(k >> 32);
        du ^= (du >> 31) ? 0x80000000u : 0xFFFFFFFFu;  // decode
        float dmin = __uint_as_float(du);
        float err = fmaxf(dmin, 0.0f);
        outz[tok] = (float)zi;
        oute[tok] = err;
        z_l[tid] = zi;
        contrib = mask[tok] * err;
    }

    // block partial of mask*errs2 (deterministic)
    #pragma unroll
    for (int off = 32; off > 0; off >>= 1) contrib += __shfl_xor(contrib, off);
    if ((tid & 63) == 0) wsum[tid >> 6] = contrib;
    __syncthreads();
    if (tid == 0) {
        float t = 0.f;
        #pragma unroll
        for (int i = 0; i < TPB / 64; ++i) t += wsum[i];
        partial[blockIdx.x] = t;
    }

    // coalesced quantized gather-write: block's 64 tokens * 64 floats = 1024 float4
    float4* qo = (float4*)(outq + (size_t)blockIdx.x * TOKS_PER_BLK * ND);
    const float4* cb4 = (const float4*)cb;
    #pragma unroll
    for (int i = 0; i < (TOKS_PER_BLK * ND / 4) / TPB; ++i) {  // 4 iters
        int g = i * TPB + tid;        // float4 index within block region
        int t = g >> 4;               // local token
        int sub = g & 15;
        int zi = z_l[t];
        qo[g] = cb4[(size_t)zi * 16 + sub];
    }
}

// ---------------------------------------------------------------------------
// Kernel 3: sum 2048 block partials deterministically; l_commit = sum/(B*L)
// ---------------------------------------------------------------------------
__global__ void fin_kernel(const float* __restrict__ partial, float* __restrict__ outl) {
    int t = threadIdx.x;                 // 1024 threads
    float x = partial[t] + partial[t + 1024];
    #pragma unroll
    for (int off = 32; off > 0; off >>= 1) x += __shfl_xor(x, off);
    __shared__ float ws[16];
    if ((t & 63) == 0) ws[t >> 6] = x;
    __syncthreads();
    if (t == 0) {
        float s = 0.f;
        #pragma unroll
        for (int i = 0; i < 16; ++i) s += ws[i];
        outl[0] = s / (float)NTOK;
    }
}

extern "C" void kernel_launch(void* const* d_in, const int* in_sizes, int n_in,
                              void* d_out, int out_size, void* d_ws, size_t ws_size,
                              hipStream_t stream) {
    const float* vecs = (const float*)d_in[0];   // [B,1,L,D] f32
    const float* mask = (const float*)d_in[1];   // [B,L] f32

    float* out = (float*)d_out;
    float* outq = out + OFF_Q;
    float* outz = out + OFF_Z;
    float* outl = out + OFF_LC;
    float* oute = out + OFF_E;

    float* cb = (float*)d_ws;            // [S*D] = 32768 f32
    float* cc = cb + NS * ND;            // [S]
    float* partial = cc + NS;            // [NBLK] = 2048

    cb_kernel<<<NS, 64, 0, stream>>>(cb, cc);
    vq_kernel<<<NBLK, TPB, 0, stream>>>(vecs, mask, cb, cc,
                                        outq, outz, oute, partial);
    fin_kernel<<<1, 1024, 0, stream>>>(partial, outl);
}

// Round 5
// 111.227 us; speedup vs baseline: 2.3007x; 1.3329x over previous
//
#include <hip/hip_runtime.h>
#include <math.h>

// SimpleVQ: B=32, H=1, L=4096, D=64, S=512
#define NB 32
#define NL 4096
#define ND 64
#define NS 512
#define NTOK (NB*NL)          // 131072

// output layout (flat f32, return order)
#define OFF_Q 0
#define OFF_Z (NTOK*ND)
#define OFF_LC (OFF_Z + NTOK)
#define OFF_E (OFF_LC + 1)

typedef __attribute__((ext_vector_type(8))) short short8;
typedef __attribute__((ext_vector_type(4))) float f32x4;
typedef unsigned int u32;
typedef unsigned short u16;

#define QCODES 128            // codes per block (quarter of codebook)
#define TOKS_PER_GRP 256      // tokens per block (4 waves x 64)
#define EPS_H 5e-4f           // >= 2x bf16-split dot error bound

// round-to-nearest-even f32 -> bf16 bits
__device__ __forceinline__ u32 f2bf_rne(float x) {
    u32 u = __float_as_uint(x);
    return (u + 0x7fffu + ((u >> 16) & 1u)) >> 16;
}

// ---------------------------------------------------------------------------
// Kernel 1: codebook. Writes: cb f32 (linear), cc f32, and PRE-SWIZZLED bf16
// hi/lo arrays so a linear LDS copy yields a bank-conflict-free layout:
// granule g (=k/8) stored at g ^ (code&7).
// ---------------------------------------------------------------------------
__global__ void cb_kernel(float* __restrict__ cb, float* __restrict__ cc,
                          u16* __restrict__ cbh, u16* __restrict__ cbl) {
    int s = blockIdx.x;        // 0..511
    int d = threadIdx.x;       // 0..63
    int j = (d < 32) ? d : (d - 32);
    double e = -(double)(2 * j) / 64.0;
    double invlam = pow(100000.0, e);
    double pre = (double)s * invlam;
    float val = (float)((d < 32) ? sin(pre) : cos(pre));

    float sq = val * val;
    #pragma unroll
    for (int off = 32; off > 0; off >>= 1) sq += __shfl_xor(sq, off);
    float mean = sq * (1.0f / 64.0f);
    float scale = (1.0f / sqrtf(mean + 1e-6f)) * 0.35355339059327379f;
    float c = val * scale;
    cb[s * ND + d] = c;

    float c2 = c * c;
    #pragma unroll
    for (int off = 32; off > 0; off >>= 1) c2 += __shfl_xor(c2, off);
    if (d == 0) cc[s] = c2;

    // bf16 hi/lo, swizzled position
    u32 hb = f2bf_rne(c);
    float hf = __uint_as_float(hb << 16);
    u32 lb = f2bf_rne(c - hf);
    int g = d >> 3, ee = d & 7;
    int pos = s * 64 + (((g ^ (s & 7)) << 3) | ee);
    cbh[pos] = (u16)hb;
    cbl[pos] = (u16)lb;
}

// ---------------------------------------------------------------------------
// Kernel 2: MFMA candidate-generation GEMM.
// grid (512 token-groups, 4 code-quarters) x 256 threads.
// Per wave: 64 tokens (4 N-tiles) in registers (bf16 hi/lo), 128 codes from
// LDS. acc init = -cc/2 so acc_final = dot - cc/2 =: h ; argmin dist == argmax h.
// Per 64-code chunk: per-token chunk-max (max tree + 2 shfl), then rescan
// appending codes with h >= max - EPS to per-token candidate lists.
// Lists written into d_out's quantized rows (overwritten later by rescore).
// ---------------------------------------------------------------------------
__launch_bounds__(256, 2)
__global__ void gemm_kernel(const float* __restrict__ vecs,
                            const u16* __restrict__ cbh,
                            const u16* __restrict__ cbl,
                            const float* __restrict__ cc,
                            float* __restrict__ outq) {
    __shared__ u16 ldsH[QCODES * 64];             // 16 KB
    __shared__ u16 ldsL[QCODES * 64];             // 16 KB
    __shared__ u32 cnt_l[TOKS_PER_GRP];           // 1 KB
    __shared__ __align__(16) u16 slots[TOKS_PER_GRP][8];  // 4 KB

    const int tid = threadIdx.x;
    const int grp = blockIdx.x;       // token group 0..511
    const int q   = blockIdx.y;       // code quarter 0..3
    const int w   = tid >> 6;
    const int lane = tid & 63;
    const int c16 = lane & 15;
    const int h   = lane >> 4;

    // stage pre-swizzled codebook quarter (linear copy) + zero counters
    {
        const short8* sH = (const short8*)(cbh + q * QCODES * 64);
        const short8* sL = (const short8*)(cbl + q * QCODES * 64);
        short8* dH = (short8*)ldsH;
        short8* dL = (short8*)ldsL;
        #pragma unroll
        for (int i = 0; i < 4; ++i) {   // 1024 chunks of 16 B
            int k = i * 256 + tid;
            dH[k] = sH[k];
            dL[k] = sL[k];
        }
        cnt_l[tid] = 0;
    }
    __syncthreads();

    // B fragments: this wave's 64 tokens as bf16 hi/lo
    // B[k][col]: col = lane&15 (token), k = kk*32 + (lane>>4)*8 + e
    short8 bh[4][2], bl[4][2];
    const int tokbase = grp * TOKS_PER_GRP + w * 64;
    #pragma unroll
    for (int nt = 0; nt < 4; ++nt) {
        const float* vp = vecs + (size_t)(tokbase + nt * 16 + c16) * ND;
        #pragma unroll
        for (int kk = 0; kk < 2; ++kk) {
            const float4* p = (const float4*)(vp + kk * 32 + h * 8);
            float4 t0 = p[0], t1 = p[1];
            float x[8] = {t0.x, t0.y, t0.z, t0.w, t1.x, t1.y, t1.z, t1.w};
            short8 H, L;
            #pragma unroll
            for (int e2 = 0; e2 < 8; ++e2) {
                u32 hb = f2bf_rne(x[e2]);
                float hf = __uint_as_float(hb << 16);
                u32 lb = f2bf_rne(x[e2] - hf);
                H[e2] = (short)hb; L[e2] = (short)lb;
            }
            bh[nt][kk] = H; bl[nt][kk] = L;
        }
    }

    f32x4 acc[4][4];
    #pragma unroll
    for (int c = 0; c < 2; ++c) {               // two 64-code chunks
        // init acc = -cc/2 (C layout: row-in-tile = h*4 + r)
        #pragma unroll
        for (int mt = 0; mt < 4; ++mt) {
            int cr = q * QCODES + c * 64 + mt * 16 + h * 4;
            f32x4 ini;
            ini[0] = -0.5f * cc[cr + 0];
            ini[1] = -0.5f * cc[cr + 1];
            ini[2] = -0.5f * cc[cr + 2];
            ini[3] = -0.5f * cc[cr + 3];
            #pragma unroll
            for (int nt = 0; nt < 4; ++nt) acc[mt][nt] = ini;
        }
        // MFMA main: A[row][k]: row = lane&15 (code), k-granule = kk*4+h (swizzled)
        #pragma unroll
        for (int mt = 0; mt < 4; ++mt) {
            int code_l = c * 64 + mt * 16 + c16;
            int sw = code_l & 7;
            short8 ah[2], al[2];
            #pragma unroll
            for (int kk = 0; kk < 2; ++kk) {
                int off = code_l * 64 + (((kk * 4 + h) ^ sw) << 3);
                ah[kk] = *(const short8*)(ldsH + off);
                al[kk] = *(const short8*)(ldsL + off);
            }
            #pragma unroll
            for (int nt = 0; nt < 4; ++nt) {
                #pragma unroll
                for (int kk = 0; kk < 2; ++kk) {
                    acc[mt][nt] = __builtin_amdgcn_mfma_f32_16x16x32_bf16(ah[kk], bh[nt][kk], acc[mt][nt], 0, 0, 0);
                    acc[mt][nt] = __builtin_amdgcn_mfma_f32_16x16x32_bf16(ah[kk], bl[nt][kk], acc[mt][nt], 0, 0, 0);
                    acc[mt][nt] = __builtin_amdgcn_mfma_f32_16x16x32_bf16(al[kk], bh[nt][kk], acc[mt][nt], 0, 0, 0);
                    acc[mt][nt] = __builtin_amdgcn_mfma_f32_16x16x32_bf16(al[kk], bl[nt][kk], acc[mt][nt], 0, 0, 0);
                }
            }
        }
        // epilogue: chunk-max per token, eps-rescan -> candidate append
        #pragma unroll
        for (int nt = 0; nt < 4; ++nt) {
            float m = acc[0][nt][0];
            #pragma unroll
            for (int mt = 0; mt < 4; ++mt) {
                m = fmaxf(m, fmaxf(fmaxf(acc[mt][nt][0], acc[mt][nt][1]),
                                   fmaxf(acc[mt][nt][2], acc[mt][nt][3])));
            }
            m = fmaxf(m, __shfl_xor(m, 16));
            m = fmaxf(m, __shfl_xor(m, 32));
            float thr = m - EPS_H;
            int tl = w * 64 + nt * 16 + c16;
            #pragma unroll
            for (int mt = 0; mt < 4; ++mt) {
                #pragma unroll
                for (int r = 0; r < 4; ++r) {
                    float v = acc[mt][nt][r];
                    if (v >= thr) {
                        u32 pos = atomicAdd(&cnt_l[tl], 1u);
                        if (pos < 8u)
                            slots[tl][pos] = (u16)(q * QCODES + c * 64 + mt * 16 + h * 4 + r);
                    }
                }
            }
        }
    }

    // write candidate lists into d_out quantized rows (bytes [0..79] of each row)
    {
        int tl = w * 64 + lane;
        u32 cnt = cnt_l[tl]; if (cnt > 8u) cnt = 8u;
        uint4 sl = *(const uint4*)&slots[tl][0];
        u32* row = (u32*)(outq + (size_t)(grp * TOKS_PER_GRP + tl) * ND);
        ((uint4*)row)[q] = sl;      // 8 u16 codes
        row[16 + q] = cnt;          // count
    }
}

// ---------------------------------------------------------------------------
// Kernel 3: exact rescore of candidates with the round-2 f32 formula
// (bit-identical dist math; index-min tie rule == jnp first-min).
// One wave per 64 tokens. Writes z, errs2, partial sums, quantized.
// ---------------------------------------------------------------------------
__global__ void rescore_kernel(const float* __restrict__ vecs,
                               const float* __restrict__ mask,
                               const float* __restrict__ cb,
                               const float* __restrict__ cc,
                               float* __restrict__ outq,
                               float* __restrict__ outz,
                               float* __restrict__ oute,
                               float* __restrict__ partial) {
    __shared__ int z_l[64];
    const int tid = threadIdx.x;        // 0..63
    const int bid = blockIdx.x;         // 0..2047
    const int tok = bid * 64 + tid;

    u32* row = (u32*)(outq + (size_t)tok * ND);
    uint4 s0 = ((const uint4*)row)[0];
    uint4 s1 = ((const uint4*)row)[1];
    uint4 s2 = ((const uint4*)row)[2];
    uint4 s3 = ((const uint4*)row)[3];
    uint4 cn = ((const uint4*)row)[4];

    float4 vf[16];
    {
        const float4* vr = (const float4*)(vecs + (size_t)tok * ND);
        #pragma unroll
        for (int i = 0; i < 16; ++i) vf[i] = vr[i];
    }
    float vv;
    {
        float a0 = 0.f, a1 = 0.f, a2 = 0.f, a3 = 0.f;
        #pragma unroll
        for (int i = 0; i < 16; ++i) {
            a0 = fmaf(vf[i].x, vf[i].x, a0);
            a1 = fmaf(vf[i].y, vf[i].y, a1);
            a2 = fmaf(vf[i].z, vf[i].z, a2);
            a3 = fmaf(vf[i].w, vf[i].w, a3);
        }
        vv = (a0 + a1) + (a2 + a3);
    }

    float bd = 3.4e38f;
    int bc = 0x7fffffff;

#define TRY_CODE(code_) do {                                                   \
        int code = (int)(code_);                                               \
        const float4* cs = (const float4*)(cb + (size_t)code * ND);            \
        float d0 = 0.f, d1 = 0.f, d2 = 0.f, d3 = 0.f;                          \
        _Pragma("unroll")                                                      \
        for (int i2 = 0; i2 < 16; ++i2) {                                      \
            float4 cv = cs[i2];                                                \
            d0 = fmaf(cv.x, vf[i2].x, d0);                                     \
            d1 = fmaf(cv.y, vf[i2].y, d1);                                     \
            d2 = fmaf(cv.z, vf[i2].z, d2);                                     \
            d3 = fmaf(cv.w, vf[i2].w, d3);                                     \
        }                                                                      \
        float dot = (d0 + d1) + (d2 + d3);                                     \
        float dist = (vv - 2.0f * dot) + cc[code];                             \
        if (dist < bd || (dist == bd && code < bc)) { bd = dist; bc = code; }  \
    } while (0)

#define DO_QUARTER(sq_, cnum_) do {                                            \
        u32 c_ = (cnum_); if (c_ > 8u) c_ = 8u;                                \
        if (0 < c_) TRY_CODE((sq_).x & 0xffffu);                               \
        if (1 < c_) TRY_CODE((sq_).x >> 16);                                   \
        if (2 < c_) TRY_CODE((sq_).y & 0xffffu);                               \
        if (3 < c_) TRY_CODE((sq_).y >> 16);                                   \
        if (4 < c_) TRY_CODE((sq_).z & 0xffffu);                               \
        if (5 < c_) TRY_CODE((sq_).z >> 16);                                   \
        if (6 < c_) TRY_CODE((sq_).w & 0xffffu);                               \
        if (7 < c_) TRY_CODE((sq_).w >> 16);                                   \
    } while (0)

    DO_QUARTER(s0, cn.x);
    DO_QUARTER(s1, cn.y);
    DO_QUARTER(s2, cn.z);
    DO_QUARTER(s3, cn.w);

    float err = fmaxf(bd, 0.0f);
    outz[tok] = (float)bc;
    oute[tok] = err;
    z_l[tid] = bc;

    float contrib = mask[tok] * err;
    #pragma unroll
    for (int off = 32; off > 0; off >>= 1) contrib += __shfl_xor(contrib, off);
    if (tid == 0) partial[bid] = contrib;

    __syncthreads();

    // coalesced quantized gather-write (overwrites the candidate bytes)
    const float4* cb4 = (const float4*)cb;
    float4* qo = (float4*)(outq + (size_t)bid * 64 * ND);
    #pragma unroll
    for (int i = 0; i < 16; ++i) {
        int g = i * 64 + tid;
        int t2 = g >> 4;
        int sub = g & 15;
        qo[g] = cb4[(size_t)z_l[t2] * 16 + sub];
    }
}

// ---------------------------------------------------------------------------
// Kernel 4: sum 2048 partials; l_commit = sum / (B*L)
// ---------------------------------------------------------------------------
__global__ void fin_kernel(const float* __restrict__ partial, float* __restrict__ outl) {
    int t = threadIdx.x;                 // 1024
    float x = partial[t] + partial[t + 1024];
    #pragma unroll
    for (int off = 32; off > 0; off >>= 1) x += __shfl_xor(x, off);
    __shared__ float ws[16];
    if ((t & 63) == 0) ws[t >> 6] = x;
    __syncthreads();
    if (t == 0) {
        float s = 0.f;
        #pragma unroll
        for (int i = 0; i < 16; ++i) s += ws[i];
        outl[0] = s / (float)NTOK;
    }
}

extern "C" void kernel_launch(void* const* d_in, const int* in_sizes, int n_in,
                              void* d_out, int out_size, void* d_ws, size_t ws_size,
                              hipStream_t stream) {
    const float* vecs = (const float*)d_in[0];   // [B,1,L,D] f32
    const float* mask = (const float*)d_in[1];   // [B,L] f32

    float* out = (float*)d_out;
    float* outq = out + OFF_Q;
    float* outz = out + OFF_Z;
    float* outl = out + OFF_LC;
    float* oute = out + OFF_E;

    // ws layout (f32 offsets): cb 32768 | cc 512 | cbh 16384 | cbl 16384 | partial 2048
    float* ws_f = (float*)d_ws;
    float* cb = ws_f;
    float* cc = ws_f + 32768;
    u16*  cbh = (u16*)(ws_f + 33280);
    u16*  cbl = (u16*)(ws_f + 49664);
    float* partial = ws_f + 66048;

    cb_kernel<<<NS, 64, 0, stream>>>(cb, cc, cbh, cbl);
    dim3 ggrid(NTOK / TOKS_PER_GRP, 4);          // (512, 4)
    gemm_kernel<<<ggrid, 256, 0, stream>>>(vecs, cbh, cbl, cc, outq);
    rescore_kernel<<<NTOK / 64, 64, 0, stream>>>(vecs, mask, cb, cc,
                                                 outq, outz, oute, partial);
    fin_kernel<<<1, 1024, 0, stream>>>(partial, outl);
}

// Round 6
// 109.906 us; speedup vs baseline: 2.3284x; 1.0120x over previous
//
#include <hip/hip_runtime.h>
#include <math.h>

// SimpleVQ: B=32, H=1, L=4096, D=64, S=512
#define NB 32
#define NL 4096
#define ND 64
#define NS 512
#define NTOK (NB*NL)          // 131072

// output layout (flat f32, return order)
#define OFF_Q 0
#define OFF_Z (NTOK*ND)
#define OFF_LC (OFF_Z + NTOK)
#define OFF_E (OFF_LC + 1)

typedef __attribute__((ext_vector_type(8))) short short8;
typedef __attribute__((ext_vector_type(4))) float f32x4;
typedef unsigned int u32;
typedef unsigned short u16;

#define QCODES 128            // codes per block (quarter of codebook)
#define TOKS_PER_GRP 256      // tokens per block
#define GEMM_TPB 512          // 8 waves; 2 N-tiles (32 tokens) per wave
#define SLOTS 10              // candidate slots per (token, quarter)
#define EPS_H 1e-3f           // >= 3-pass bf16-split dot error bound

#define RS_TPB 256
#define RS_TOKS 128           // tokens per rescore block (2 threads/token)
#define NPART (NTOK / RS_TOKS) // 1024 partials

// round-to-nearest-even f32 -> bf16 bits
__device__ __forceinline__ u32 f2bf_rne(float x) {
    u32 u = __float_as_uint(x);
    return (u + 0x7fffu + ((u >> 16) & 1u)) >> 16;
}

// ---------------------------------------------------------------------------
// Kernel 1: codebook. cb f32 (linear), cc f32, PRE-SWIZZLED bf16 hi/lo
// (granule g stored at g ^ (code&7)) so a linear LDS copy is conflict-free.
// ---------------------------------------------------------------------------
__global__ void cb_kernel(float* __restrict__ cb, float* __restrict__ cc,
                          u16* __restrict__ cbh, u16* __restrict__ cbl) {
    int s = blockIdx.x;        // 0..511
    int d = threadIdx.x;       // 0..63
    int j = (d < 32) ? d : (d - 32);
    double e = -(double)(2 * j) / 64.0;
    double invlam = pow(100000.0, e);
    double pre = (double)s * invlam;
    float val = (float)((d < 32) ? sin(pre) : cos(pre));

    float sq = val * val;
    #pragma unroll
    for (int off = 32; off > 0; off >>= 1) sq += __shfl_xor(sq, off);
    float mean = sq * (1.0f / 64.0f);
    float scale = (1.0f / sqrtf(mean + 1e-6f)) * 0.35355339059327379f;
    float c = val * scale;
    cb[s * ND + d] = c;

    float c2 = c * c;
    #pragma unroll
    for (int off = 32; off > 0; off >>= 1) c2 += __shfl_xor(c2, off);
    if (d == 0) cc[s] = c2;

    u32 hb = f2bf_rne(c);
    float hf = __uint_as_float(hb << 16);
    u32 lb = f2bf_rne(c - hf);
    int g = d >> 3, ee = d & 7;
    int pos = s * 64 + (((g ^ (s & 7)) << 3) | ee);
    cbh[pos] = (u16)hb;
    cbl[pos] = (u16)lb;
}

// ---------------------------------------------------------------------------
// Kernel 2: MFMA candidate GEMM. grid (512 groups, 4 quarters) x 512 threads.
// 8 waves; wave w owns 32 tokens (2 N-tiles). acc init = -cc/2 so
// h = dot - cc/2; argmin dist == argmax h. 3-pass bf16 split (al*bl dropped,
// covered by EPS_H). Per 64-code chunk: per-token max + eps-rescan appending
// candidates (<=SLOTS) -> lists in d_out quantized rows (overwritten later).
// ---------------------------------------------------------------------------
__launch_bounds__(GEMM_TPB, 4)
__global__ void gemm_kernel(const float* __restrict__ vecs,
                            const u16* __restrict__ cbh,
                            const u16* __restrict__ cbl,
                            const float* __restrict__ cc,
                            float* __restrict__ outq) {
    __shared__ u16 ldsH[QCODES * 64];                       // 16 KB
    __shared__ u16 ldsL[QCODES * 64];                       // 16 KB
    __shared__ u32 cnt_l[TOKS_PER_GRP];                     // 1 KB
    __shared__ __align__(16) u16 slots[TOKS_PER_GRP][SLOTS]; // 5 KB

    const int tid = threadIdx.x;
    const int grp = blockIdx.x;       // token group 0..511
    const int q   = blockIdx.y;       // code quarter 0..3
    const int w   = tid >> 6;         // wave 0..7
    const int lane = tid & 63;
    const int c16 = lane & 15;
    const int h   = lane >> 4;

    // stage pre-swizzled codebook quarter (linear copy) + zero counters
    {
        const short8* sH = (const short8*)(cbh + q * QCODES * 64);
        const short8* sL = (const short8*)(cbl + q * QCODES * 64);
        short8* dH = (short8*)ldsH;
        short8* dL = (short8*)ldsL;
        #pragma unroll
        for (int i = 0; i < 2; ++i) {   // 1024 chunks of 16 B / 512 threads
            int k = i * GEMM_TPB + tid;
            dH[k] = sH[k];
            dL[k] = sL[k];
        }
        if (tid < TOKS_PER_GRP) cnt_l[tid] = 0;
    }
    __syncthreads();

    // B fragments: wave's 32 tokens as bf16 hi/lo
    // B[k][col]: col = lane&15 (token), k = kk*32 + (lane>>4)*8 + e
    short8 bh[2][2], bl[2][2];
    const int tokbase = grp * TOKS_PER_GRP + w * 32;
    #pragma unroll
    for (int nt = 0; nt < 2; ++nt) {
        const float* vp = vecs + (size_t)(tokbase + nt * 16 + c16) * ND;
        #pragma unroll
        for (int kk = 0; kk < 2; ++kk) {
            const float4* p = (const float4*)(vp + kk * 32 + h * 8);
            float4 t0 = p[0], t1 = p[1];
            float x[8] = {t0.x, t0.y, t0.z, t0.w, t1.x, t1.y, t1.z, t1.w};
            short8 H, L;
            #pragma unroll
            for (int e2 = 0; e2 < 8; ++e2) {
                u32 hb = f2bf_rne(x[e2]);
                float hf = __uint_as_float(hb << 16);
                u32 lb = f2bf_rne(x[e2] - hf);
                H[e2] = (short)hb; L[e2] = (short)lb;
            }
            bh[nt][kk] = H; bl[nt][kk] = L;
        }
    }

    f32x4 acc[4][2];
    #pragma unroll
    for (int c = 0; c < 2; ++c) {               // two 64-code chunks
        #pragma unroll
        for (int mt = 0; mt < 4; ++mt) {
            int cr = q * QCODES + c * 64 + mt * 16 + h * 4;
            f32x4 ini;
            ini[0] = -0.5f * cc[cr + 0];
            ini[1] = -0.5f * cc[cr + 1];
            ini[2] = -0.5f * cc[cr + 2];
            ini[3] = -0.5f * cc[cr + 3];
            #pragma unroll
            for (int nt = 0; nt < 2; ++nt) acc[mt][nt] = ini;
        }
        // A[row][k]: row = lane&15 (code), k-granule = kk*4+h (swizzled)
        #pragma unroll
        for (int mt = 0; mt < 4; ++mt) {
            int code_l = c * 64 + mt * 16 + c16;
            int sw = code_l & 7;
            short8 ah[2], al[2];
            #pragma unroll
            for (int kk = 0; kk < 2; ++kk) {
                int off = code_l * 64 + (((kk * 4 + h) ^ sw) << 3);
                ah[kk] = *(const short8*)(ldsH + off);
                al[kk] = *(const short8*)(ldsL + off);
            }
            #pragma unroll
            for (int nt = 0; nt < 2; ++nt) {
                #pragma unroll
                for (int kk = 0; kk < 2; ++kk) {
                    acc[mt][nt] = __builtin_amdgcn_mfma_f32_16x16x32_bf16(ah[kk], bh[nt][kk], acc[mt][nt], 0, 0, 0);
                    acc[mt][nt] = __builtin_amdgcn_mfma_f32_16x16x32_bf16(ah[kk], bl[nt][kk], acc[mt][nt], 0, 0, 0);
                    acc[mt][nt] = __builtin_amdgcn_mfma_f32_16x16x32_bf16(al[kk], bh[nt][kk], acc[mt][nt], 0, 0, 0);
                }
            }
        }
        // epilogue: chunk-max per token, eps-rescan -> candidate append
        #pragma unroll
        for (int nt = 0; nt < 2; ++nt) {
            float m = acc[0][nt][0];
            #pragma unroll
            for (int mt = 0; mt < 4; ++mt) {
                m = fmaxf(m, fmaxf(fmaxf(acc[mt][nt][0], acc[mt][nt][1]),
                                   fmaxf(acc[mt][nt][2], acc[mt][nt][3])));
            }
            m = fmaxf(m, __shfl_xor(m, 16));
            m = fmaxf(m, __shfl_xor(m, 32));
            float thr = m - EPS_H;
            int tl = w * 32 + nt * 16 + c16;
            #pragma unroll
            for (int mt = 0; mt < 4; ++mt) {
                #pragma unroll
                for (int r = 0; r < 4; ++r) {
                    float v = acc[mt][nt][r];
                    if (v >= thr) {
                        u32 pos = atomicAdd(&cnt_l[tl], 1u);
                        if (pos < (u32)SLOTS)
                            slots[tl][pos] = (u16)(q * QCODES + c * 64 + mt * 16 + h * 4 + r);
                    }
                }
            }
        }
    }
    __syncthreads();

    // write candidate lists into d_out quantized rows:
    // row u32s: [q*5 .. q*5+4] = 10 u16 codes, [20+q] = count   (96 B / 256 B row)
    if (tid < TOKS_PER_GRP) {
        int tl = tid;
        u32 cnt = cnt_l[tl]; if (cnt > (u32)SLOTS) cnt = (u32)SLOTS;
        const u32* s32 = (const u32*)&slots[tl][0];
        u32* row = (u32*)(outq + (size_t)(grp * TOKS_PER_GRP + tl) * ND);
        #pragma unroll
        for (int j2 = 0; j2 < 5; ++j2) row[q * 5 + j2] = s32[j2];
        row[20 + q] = cnt;
    }
}

// ---------------------------------------------------------------------------
// Kernel 3: exact rescore. 2 threads/token (2 quarters each), per-candidate
// dist arithmetic byte-identical to the round-5 full chain; winner selection
// via packed (dist,idx) key min == lexicographic min == jnp first-min rule.
// ---------------------------------------------------------------------------
__device__ __forceinline__ float dist_code(const float* __restrict__ cb,
                                           const float* __restrict__ cc,
                                           const float4* vf, float vv, int code) {
    const float4* cs = (const float4*)(cb + (size_t)code * ND);
    float d0 = 0.f, d1 = 0.f, d2 = 0.f, d3 = 0.f;
    #pragma unroll
    for (int i = 0; i < 16; ++i) {
        float4 cv = cs[i];
        d0 = fmaf(cv.x, vf[i].x, d0);
        d1 = fmaf(cv.y, vf[i].y, d1);
        d2 = fmaf(cv.z, vf[i].z, d2);
        d3 = fmaf(cv.w, vf[i].w, d3);
    }
    float dot = (d0 + d1) + (d2 + d3);
    return (vv - 2.0f * dot) + cc[code];
}

__device__ __forceinline__ void upd_key(unsigned long long& best, float dist, int code) {
    u32 u = __float_as_uint(dist);
    u ^= (u >> 31) ? 0xFFFFFFFFu : 0x80000000u;   // monotone f32 -> u32
    unsigned long long k = ((unsigned long long)u << 32) | (u32)code;
    if (k < best) best = k;
}

__launch_bounds__(RS_TPB, 4)
__global__ void rescore_kernel(const float* __restrict__ vecs,
                               const float* __restrict__ mask,
                               const float* __restrict__ cb,
                               const float* __restrict__ cc,
                               float* __restrict__ outq,
                               float* __restrict__ outz,
                               float* __restrict__ oute,
                               float* __restrict__ partial) {
    __shared__ int z_l[RS_TOKS];
    __shared__ float wsum[RS_TPB / 64];
    const int tid  = threadIdx.x;
    const int bid  = blockIdx.x;        // 0..1023
    const int p    = tid >> 1;          // token-local 0..127
    const int half = tid & 1;           // which 2 quarters
    const int tok  = bid * RS_TOKS + p;

    const u32* row32 = (const u32*)(outq + (size_t)tok * ND);
    const int q0 = half * 2, q1 = q0 + 1;
    u32 w0[5], w1[5];
    #pragma unroll
    for (int j2 = 0; j2 < 5; ++j2) { w0[j2] = row32[q0 * 5 + j2]; w1[j2] = row32[q1 * 5 + j2]; }
    u32 c0 = row32[20 + q0]; if (c0 > (u32)SLOTS) c0 = (u32)SLOTS;
    u32 c1 = row32[20 + q1]; if (c1 > (u32)SLOTS) c1 = (u32)SLOTS;

    float4 vf[16];
    {
        const float4* vr = (const float4*)(vecs + (size_t)tok * ND);
        #pragma unroll
        for (int i = 0; i < 16; ++i) vf[i] = vr[i];
    }
    float vv;
    {
        float a0 = 0.f, a1 = 0.f, a2 = 0.f, a3 = 0.f;
        #pragma unroll
        for (int i = 0; i < 16; ++i) {
            a0 = fmaf(vf[i].x, vf[i].x, a0);
            a1 = fmaf(vf[i].y, vf[i].y, a1);
            a2 = fmaf(vf[i].z, vf[i].z, a2);
            a3 = fmaf(vf[i].w, vf[i].w, a3);
        }
        vv = (a0 + a1) + (a2 + a3);
    }

    unsigned long long best = 0xFFFFFFFFFFFFFFFFull;

#define PROC_QUARTER(warr, cnum) do {                                          \
        u32 c_ = (cnum);                                                       \
        _Pragma("unroll")                                                      \
        for (int j = 0; j < SLOTS; j += 2) {                                   \
            if ((u32)j < c_) {                                                 \
                u32 wj = warr[j >> 1];                                         \
                int code0 = (int)(wj & 0xffffu);                               \
                int code1 = (int)(wj >> 16);                                   \
                bool two = ((u32)(j + 1) < c_);                                \
                if (!two) code1 = code0;                                       \
                float dist0 = dist_code(cb, cc, vf, vv, code0);                \
                float dist1 = dist_code(cb, cc, vf, vv, code1);                \
                upd_key(best, dist0, code0);                                   \
                if (two) upd_key(best, dist1, code1);                          \
            }                                                                  \
        }                                                                      \
    } while (0)

    PROC_QUARTER(w0, c0);
    PROC_QUARTER(w1, c1);

    // combine the two halves of the token
    {
        unsigned long long other = __shfl_xor(best, 1);
        if (other < best) best = other;
    }

    float contrib = 0.0f;
    if (half == 0) {
        int zi = (int)(best & 0xFFFFFFFFu);
        u32 du = (u32)(best >> 32);
        du ^= (du >> 31) ? 0x80000000u : 0xFFFFFFFFu;
        float dmin = __uint_as_float(du);
        float err = fmaxf(dmin, 0.0f);
        outz[tok] = (float)zi;
        oute[tok] = err;
        z_l[p] = zi;
        contrib = mask[tok] * err;
    }

    #pragma unroll
    for (int off = 32; off > 0; off >>= 1) contrib += __shfl_xor(contrib, off);
    if ((tid & 63) == 0) wsum[tid >> 6] = contrib;
    __syncthreads();
    if (tid == 0) {
        float t = 0.f;
        #pragma unroll
        for (int i = 0; i < RS_TPB / 64; ++i) t += wsum[i];
        partial[bid] = t;
    }

    // coalesced quantized gather-write (overwrites the candidate bytes)
    const float4* cb4 = (const float4*)cb;
    float4* qo = (float4*)(outq + (size_t)bid * RS_TOKS * ND);
    #pragma unroll
    for (int i = 0; i < (RS_TOKS * ND / 4) / RS_TPB; ++i) {   // 8 iters
        int g = i * RS_TPB + tid;
        int t2 = g >> 4;
        int sub = g & 15;
        qo[g] = cb4[(size_t)z_l[t2] * 16 + sub];
    }
}

// ---------------------------------------------------------------------------
// Kernel 4: sum 1024 partials; l_commit = sum / (B*L)
// ---------------------------------------------------------------------------
__global__ void fin_kernel(const float* __restrict__ partial, float* __restrict__ outl) {
    int t = threadIdx.x;                 // 1024
    float x = partial[t];
    #pragma unroll
    for (int off = 32; off > 0; off >>= 1) x += __shfl_xor(x, off);
    __shared__ float ws[16];
    if ((t & 63) == 0) ws[t >> 6] = x;
    __syncthreads();
    if (t == 0) {
        float s = 0.f;
        #pragma unroll
        for (int i = 0; i < 16; ++i) s += ws[i];
        outl[0] = s / (float)NTOK;
    }
}

extern "C" void kernel_launch(void* const* d_in, const int* in_sizes, int n_in,
                              void* d_out, int out_size, void* d_ws, size_t ws_size,
                              hipStream_t stream) {
    const float* vecs = (const float*)d_in[0];   // [B,1,L,D] f32
    const float* mask = (const float*)d_in[1];   // [B,L] f32

    float* out = (float*)d_out;
    float* outq = out + OFF_Q;
    float* outz = out + OFF_Z;
    float* outl = out + OFF_LC;
    float* oute = out + OFF_E;

    // ws layout (f32 offsets): cb 32768 | cc 512 | cbh 16384 | cbl 16384 | partial
    float* ws_f = (float*)d_ws;
    float* cb = ws_f;
    float* cc = ws_f + 32768;
    u16*  cbh = (u16*)(ws_f + 33280);
    u16*  cbl = (u16*)(ws_f + 49664);
    float* partial = ws_f + 66048;

    cb_kernel<<<NS, 64, 0, stream>>>(cb, cc, cbh, cbl);
    dim3 ggrid(NTOK / TOKS_PER_GRP, 4);          // (512, 4)
    gemm_kernel<<<ggrid, GEMM_TPB, 0, stream>>>(vecs, cbh, cbl, cc, outq);
    rescore_kernel<<<NTOK / RS_TOKS, RS_TPB, 0, stream>>>(vecs, mask, cb, cc,
                                                          outq, outz, oute, partial);
    fin_kernel<<<1, NPART, 0, stream>>>(partial, outl);
}

// Round 7
// 75.936 us; speedup vs baseline: 3.3700x; 1.4474x over previous
//
#include <hip/hip_runtime.h>
#include <math.h>

// SimpleVQ: B=32, H=1, L=4096, D=64, S=512
#define NB 32
#define NL 4096
#define ND 64
#define NS 512
#define NTOK (NB*NL)          // 131072

// output layout (flat f32, return order)
#define OFF_Q 0
#define OFF_Z (NTOK*ND)
#define OFF_LC (OFF_Z + NTOK)
#define OFF_E (OFF_LC + 1)

typedef __attribute__((ext_vector_type(8))) short short8;
typedef __attribute__((ext_vector_type(4))) float f32x4;
typedef unsigned int u32;
typedef unsigned short u16;
typedef unsigned long long u64;

#define QCODES 128            // codes per staged quarter
#define TOKS 256              // tokens per block
#define TPB 1024              // 16 waves
#define SLOTS 32              // candidate slots per token (across all 8 chunks)
#define EPS_H 1e-3f           // >= 2x 3-pass bf16-split h-error bound
#define NBLK (NTOK / TOKS)    // 512 blocks

// round-to-nearest-even f32 -> bf16 bits
__device__ __forceinline__ u32 f2bf_rne(float x) {
    u32 u = __float_as_uint(x);
    return (u + 0x7fffu + ((u >> 16) & 1u)) >> 16;
}

__device__ __forceinline__ void upd_key(u64& best, float dist, int code) {
    u32 u = __float_as_uint(dist);
    u ^= (u >> 31) ? 0xFFFFFFFFu : 0x80000000u;   // monotone f32 -> u32
    u64 k = ((u64)u << 32) | (u32)code;
    if (k < best) best = k;
}

// ---------------------------------------------------------------------------
// Kernel 1: codebook. cb f32 (linear), cc f32, PRE-SWIZZLED bf16 hi/lo
// (granule g stored at g ^ (code&7)) so a linear LDS copy is conflict-free.
// ---------------------------------------------------------------------------
__global__ void cb_kernel(float* __restrict__ cb, float* __restrict__ cc,
                          u16* __restrict__ cbh, u16* __restrict__ cbl) {
    int s = blockIdx.x;        // 0..511
    int d = threadIdx.x;       // 0..63
    int j = (d < 32) ? d : (d - 32);
    double e = -(double)(2 * j) / 64.0;
    double invlam = pow(100000.0, e);
    double pre = (double)s * invlam;
    float val = (float)((d < 32) ? sin(pre) : cos(pre));

    float sq = val * val;
    #pragma unroll
    for (int off = 32; off > 0; off >>= 1) sq += __shfl_xor(sq, off);
    float mean = sq * (1.0f / 64.0f);
    float scale = (1.0f / sqrtf(mean + 1e-6f)) * 0.35355339059327379f;
    float c = val * scale;
    cb[s * ND + d] = c;

    float c2 = c * c;
    #pragma unroll
    for (int off = 32; off > 0; off >>= 1) c2 += __shfl_xor(c2, off);
    if (d == 0) cc[s] = c2;

    u32 hb = f2bf_rne(c);
    float hf = __uint_as_float(hb << 16);
    u32 lb = f2bf_rne(c - hf);
    int g = d >> 3, ee = d & 7;
    int pos = s * 64 + (((g ^ (s & 7)) << 3) | ee);
    cbh[pos] = (u16)hb;
    cbl[pos] = (u16)lb;
}

// ---------------------------------------------------------------------------
// Kernel 2 (FUSED): per block: 256 tokens, 16 waves.
//  P0: stage vecs f32 -> LDS (XOR-swizzled), convert B-frags once.
//  P1: loop 4 quarters: stage bf16 hi/lo quarter -> MFMA (h = dot - cc/2)
//      -> per-chunk max + eps-rescan -> candidates (code, h) in LDS.
//  P2: global-h filter + exact f32 rescore (round-6-identical dist chain),
//      packed-key min (first-min tie rule), 4 threads/token.
//  P3: z / errs2 / partial / coalesced quantized gather-write.
// ---------------------------------------------------------------------------
__launch_bounds__(TPB)
__global__ void fused_kernel(const float* __restrict__ vecs,
                             const float* __restrict__ mask,
                             const float* __restrict__ cb,
                             const float* __restrict__ cc,
                             const u16* __restrict__ cbh,
                             const u16* __restrict__ cbl,
                             float* __restrict__ outq,
                             float* __restrict__ outz,
                             float* __restrict__ oute,
                             float* __restrict__ partial) {
    __shared__ float4 svec[TOKS * 16];          // 64 KB, swizzled f4: g ^ (row&15)
    __shared__ u16 ldsH[QCODES * 64];           // 16 KB
    __shared__ u16 ldsL[QCODES * 64];           // 16 KB
    __shared__ u16 slots[TOKS][SLOTS];          // 16 KB
    __shared__ float hval[TOKS][SLOTS];         // 32 KB
    __shared__ u32 cnt_l[TOKS];                 // 1 KB
    __shared__ int z_l[TOKS];                   // 1 KB
    __shared__ float wsum[TPB / 64];

    const int tid = threadIdx.x;
    const int grp = blockIdx.x;      // 0..511
    const int w = tid >> 6;          // wave 0..15
    const int lane = tid & 63;
    const int c16 = lane & 15;
    const int h = lane >> 4;

    // ---- P0a: stage vecs -> LDS (swizzled), coalesced ----
    {
        const float4* vsrc = (const float4*)(vecs + (size_t)grp * TOKS * ND);
        #pragma unroll
        for (int i = 0; i < 4; ++i) {
            int idx = i * TPB + tid;            // 4096 f4
            int row = idx >> 4, g = idx & 15;
            svec[row * 16 + (g ^ (row & 15))] = vsrc[idx];
        }
        if (tid < TOKS) cnt_l[tid] = 0;
    }
    // stage quarter 0
    ((short8*)ldsH)[tid] = ((const short8*)cbh)[tid];
    ((short8*)ldsL)[tid] = ((const short8*)cbl)[tid];
    __syncthreads();

    // ---- P0b: B fragments (once). B[k][col]: col=c16 (token), k=kk*32+h*8+e ----
    const int trow = w * 16 + c16;   // this lane's token 0..255
    short8 bh[2], bl[2];
    #pragma unroll
    for (int kk = 0; kk < 2; ++kk) {
        float x[8];
        #pragma unroll
        for (int u = 0; u < 2; ++u) {
            int g = kk * 8 + h * 2 + u;
            float4 t = svec[trow * 16 + (g ^ (trow & 15))];
            x[u * 4 + 0] = t.x; x[u * 4 + 1] = t.y;
            x[u * 4 + 2] = t.z; x[u * 4 + 3] = t.w;
        }
        short8 H, L;
        #pragma unroll
        for (int e2 = 0; e2 < 8; ++e2) {
            u32 hb = f2bf_rne(x[e2]);
            float hf = __uint_as_float(hb << 16);
            u32 lb = f2bf_rne(x[e2] - hf);
            H[e2] = (short)hb; L[e2] = (short)lb;
        }
        bh[kk] = H; bl[kk] = L;
    }

    // ---- P1: quarters ----
    for (int q = 0; q < 4; ++q) {
        if (q) {
            __syncthreads();   // previous MFMA done with ldsH/L
            ((short8*)ldsH)[tid] = ((const short8*)(cbh + q * QCODES * 64))[tid];
            ((short8*)ldsL)[tid] = ((const short8*)(cbl + q * QCODES * 64))[tid];
            __syncthreads();
        }
        #pragma unroll
        for (int c = 0; c < 2; ++c) {             // two 64-code chunks
            f32x4 acc[4];
            #pragma unroll
            for (int mt = 0; mt < 4; ++mt) {
                int cr = q * QCODES + c * 64 + mt * 16 + h * 4;
                f32x4 ini;
                ini[0] = -0.5f * cc[cr + 0];
                ini[1] = -0.5f * cc[cr + 1];
                ini[2] = -0.5f * cc[cr + 2];
                ini[3] = -0.5f * cc[cr + 3];
                acc[mt] = ini;
            }
            #pragma unroll
            for (int mt = 0; mt < 4; ++mt) {
                int code_l = c * 64 + mt * 16 + c16;
                int sw = code_l & 7;
                short8 ah[2], al[2];
                #pragma unroll
                for (int kk = 0; kk < 2; ++kk) {
                    int off = code_l * 64 + (((kk * 4 + h) ^ sw) << 3);
                    ah[kk] = *(const short8*)(ldsH + off);
                    al[kk] = *(const short8*)(ldsL + off);
                }
                #pragma unroll
                for (int kk = 0; kk < 2; ++kk) {
                    acc[mt] = __builtin_amdgcn_mfma_f32_16x16x32_bf16(ah[kk], bh[kk], acc[mt], 0, 0, 0);
                    acc[mt] = __builtin_amdgcn_mfma_f32_16x16x32_bf16(ah[kk], bl[kk], acc[mt], 0, 0, 0);
                    acc[mt] = __builtin_amdgcn_mfma_f32_16x16x32_bf16(al[kk], bh[kk], acc[mt], 0, 0, 0);
                }
            }
            // epilogue: chunk-max per token, eps-rescan -> candidate append
            float m = acc[0][0];
            #pragma unroll
            for (int mt = 0; mt < 4; ++mt) {
                m = fmaxf(m, fmaxf(fmaxf(acc[mt][0], acc[mt][1]),
                                   fmaxf(acc[mt][2], acc[mt][3])));
            }
            m = fmaxf(m, __shfl_xor(m, 16));
            m = fmaxf(m, __shfl_xor(m, 32));
            float thr = m - EPS_H;
            #pragma unroll
            for (int mt = 0; mt < 4; ++mt) {
                #pragma unroll
                for (int r = 0; r < 4; ++r) {
                    float v = acc[mt][r];
                    if (v >= thr) {
                        u32 pos = atomicAdd(&cnt_l[trow], 1u);
                        if (pos < (u32)SLOTS) {
                            slots[trow][pos] = (u16)(q * QCODES + c * 64 + mt * 16 + h * 4 + r);
                            hval[trow][pos] = v;
                        }
                    }
                }
            }
        }
    }
    __syncthreads();

    // ---- P2: exact rescore, 4 threads/token ----
    const int p  = tid >> 2;          // token-local 0..255
    const int qs = tid & 3;
    const int tok = grp * TOKS + p;

    float4 vf[16];
    #pragma unroll
    for (int g = 0; g < 16; ++g) vf[g] = svec[p * 16 + (g ^ (p & 15))];
    float vv;
    {
        float a0 = 0.f, a1 = 0.f, a2 = 0.f, a3 = 0.f;
        #pragma unroll
        for (int i = 0; i < 16; ++i) {
            a0 = fmaf(vf[i].x, vf[i].x, a0);
            a1 = fmaf(vf[i].y, vf[i].y, a1);
            a2 = fmaf(vf[i].z, vf[i].z, a2);
            a3 = fmaf(vf[i].w, vf[i].w, a3);
        }
        vv = (a0 + a1) + (a2 + a3);
    }

    u32 cnt = cnt_l[p]; if (cnt > (u32)SLOTS) cnt = (u32)SLOTS;
    float hm = -3.4e38f;
    for (u32 j2 = 0; j2 < cnt; ++j2) hm = fmaxf(hm, hval[p][j2]);
    float thr2 = hm - EPS_H;

    u64 best = 0xFFFFFFFFFFFFFFFFull;
    for (u32 j2 = qs; j2 < cnt; j2 += 4) {
        if (hval[p][j2] >= thr2) {
            int code = (int)slots[p][j2];
            const float4* cs = (const float4*)(cb + (size_t)code * ND);
            float d0 = 0.f, d1 = 0.f, d2 = 0.f, d3 = 0.f;
            #pragma unroll
            for (int i2 = 0; i2 < 16; ++i2) {
                float4 cv = cs[i2];
                d0 = fmaf(cv.x, vf[i2].x, d0);
                d1 = fmaf(cv.y, vf[i2].y, d1);
                d2 = fmaf(cv.z, vf[i2].z, d2);
                d3 = fmaf(cv.w, vf[i2].w, d3);
            }
            float dot = (d0 + d1) + (d2 + d3);
            float dist = (vv - 2.0f * dot) + cc[code];
            upd_key(best, dist, code);
        }
    }
    {
        u64 o = __shfl_xor(best, 1); if (o < best) best = o;
        o = __shfl_xor(best, 2); if (o < best) best = o;
    }

    float contrib = 0.0f;
    if (qs == 0) {
        int zi = (int)(best & 0xFFFFFFFFu);
        u32 du = (u32)(best >> 32);
        du ^= (du >> 31) ? 0x80000000u : 0xFFFFFFFFu;
        float dmin = __uint_as_float(du);
        float err = fmaxf(dmin, 0.0f);
        outz[tok] = (float)zi;
        oute[tok] = err;
        z_l[p] = zi;
        contrib = mask[tok] * err;
    }
    #pragma unroll
    for (int off = 32; off > 0; off >>= 1) contrib += __shfl_xor(contrib, off);
    if (lane == 0) wsum[w] = contrib;
    __syncthreads();
    if (tid == 0) {
        float t = 0.f;
        #pragma unroll
        for (int i = 0; i < TPB / 64; ++i) t += wsum[i];
        partial[grp] = t;
    }

    // ---- P3: coalesced quantized gather-write ----
    const float4* cb4 = (const float4*)cb;
    float4* qo = (float4*)(outq + (size_t)grp * TOKS * ND);
    #pragma unroll
    for (int i = 0; i < 4; ++i) {
        int gidx = i * TPB + tid;
        int t2 = gidx >> 4;
        int sub = gidx & 15;
        qo[gidx] = cb4[(size_t)z_l[t2] * 16 + sub];
    }
}

// ---------------------------------------------------------------------------
// Kernel 3: sum 512 partials; l_commit = sum / (B*L)
// ---------------------------------------------------------------------------
__global__ void fin_kernel(const float* __restrict__ partial, float* __restrict__ outl) {
    int t = threadIdx.x;                 // 512
    float x = partial[t];
    #pragma unroll
    for (int off = 32; off > 0; off >>= 1) x += __shfl_xor(x, off);
    __shared__ float ws[8];
    if ((t & 63) == 0) ws[t >> 6] = x;
    __syncthreads();
    if (t == 0) {
        float s = 0.f;
        #pragma unroll
        for (int i = 0; i < 8; ++i) s += ws[i];
        outl[0] = s / (float)NTOK;
    }
}

extern "C" void kernel_launch(void* const* d_in, const int* in_sizes, int n_in,
                              void* d_out, int out_size, void* d_ws, size_t ws_size,
                              hipStream_t stream) {
    const float* vecs = (const float*)d_in[0];   // [B,1,L,D] f32
    const float* mask = (const float*)d_in[1];   // [B,L] f32

    float* out = (float*)d_out;
    float* outq = out + OFF_Q;
    float* outz = out + OFF_Z;
    float* outl = out + OFF_LC;
    float* oute = out + OFF_E;

    // ws layout (f32 offsets): cb 32768 | cc 512 | cbh 16384 | cbl 16384 | partial
    float* ws_f = (float*)d_ws;
    float* cb = ws_f;
    float* cc = ws_f + 32768;
    u16*  cbh = (u16*)(ws_f + 33280);
    u16*  cbl = (u16*)(ws_f + 49664);
    float* partial = ws_f + 66048;

    cb_kernel<<<NS, 64, 0, stream>>>(cb, cc, cbh, cbl);
    fused_kernel<<<NBLK, TPB, 0, stream>>>(vecs, mask, cb, cc, cbh, cbl,
                                           outq, outz, oute, partial);
    fin_kernel<<<1, 512, 0, stream>>>(partial, outl);
}

// Round 8
// 68.754 us; speedup vs baseline: 3.7220x; 1.1045x over previous
//
#include <hip/hip_runtime.h>
#include <math.h>

// SimpleVQ: B=32, H=1, L=4096, D=64, S=512
#define NB 32
#define NL 4096
#define ND 64
#define NS 512
#define NTOK (NB*NL)          // 131072

// output layout (flat f32, return order)
#define OFF_Q 0
#define OFF_Z (NTOK*ND)
#define OFF_LC (OFF_Z + NTOK)
#define OFF_E (OFF_LC + 1)

typedef __attribute__((ext_vector_type(8))) short short8;
typedef __attribute__((ext_vector_type(4))) float f32x4;
typedef unsigned int u32;
typedef unsigned short u16;
typedef unsigned long long u64;

#define QCODES 128            // codes per staged quarter
#define TOKS 128              // tokens per block
#define TPB 512               // 8 waves
#define SLOTS 12              // candidate slots per token
#define SLOTP 13              // padded stride (odd -> conflict-free scans)
#define EPS_H 1e-3f           // >= 2x 3-pass bf16-split h-error bound
#define NBLK (NTOK / TOKS)    // 1024 blocks

// round-to-nearest-even f32 -> bf16 bits
__device__ __forceinline__ u32 f2bf_rne(float x) {
    u32 u = __float_as_uint(x);
    return (u + 0x7fffu + ((u >> 16) & 1u)) >> 16;
}

__device__ __forceinline__ void upd_key(u64& best, float dist, int code) {
    u32 u = __float_as_uint(dist);
    u ^= (u >> 31) ? 0xFFFFFFFFu : 0x80000000u;   // monotone f32 -> u32
    u64 k = ((u64)u << 32) | (u32)code;
    if (k < best) best = k;
}

// ---------------------------------------------------------------------------
// Kernel 1: codebook. cb f32 (linear), cc f32, PRE-SWIZZLED bf16 hi/lo
// (granule g stored at g ^ (code&7)) so a linear LDS copy is conflict-free.
// ---------------------------------------------------------------------------
__global__ void cb_kernel(float* __restrict__ cb, float* __restrict__ cc,
                          u16* __restrict__ cbh, u16* __restrict__ cbl) {
    int s = blockIdx.x;        // 0..511
    int d = threadIdx.x;       // 0..63
    int j = (d < 32) ? d : (d - 32);
    double e = -(double)(2 * j) / 64.0;
    double invlam = pow(100000.0, e);
    double pre = (double)s * invlam;
    float val = (float)((d < 32) ? sin(pre) : cos(pre));

    float sq = val * val;
    #pragma unroll
    for (int off = 32; off > 0; off >>= 1) sq += __shfl_xor(sq, off);
    float mean = sq * (1.0f / 64.0f);
    float scale = (1.0f / sqrtf(mean + 1e-6f)) * 0.35355339059327379f;
    float c = val * scale;
    cb[s * ND + d] = c;

    float c2 = c * c;
    #pragma unroll
    for (int off = 32; off > 0; off >>= 1) c2 += __shfl_xor(c2, off);
    if (d == 0) cc[s] = c2;

    u32 hb = f2bf_rne(c);
    float hf = __uint_as_float(hb << 16);
    u32 lb = f2bf_rne(c - hf);
    int g = d >> 3, ee = d & 7;
    int pos = s * 64 + (((g ^ (s & 7)) << 3) | ee);
    cbh[pos] = (u16)hb;
    cbl[pos] = (u16)lb;
}

// ---------------------------------------------------------------------------
// Kernel 2 (FUSED): per block: 128 tokens, 8 waves, ~78 KB LDS -> 2 blocks/CU.
//  P0: stage vecs f32 -> LDS (XOR-swizzled), convert B-frags once.
//  P1: loop 4 quarters: stage bf16 hi/lo quarter -> MFMA (h = dot - cc/2)
//      -> per-chunk max + eps-rescan -> candidates (code, h) in LDS.
//  P2: global-h filter + exact f32 rescore (identical dist chain),
//      packed-key min (first-min tie rule), 4 threads/token.
//  P3: z / errs2 / partial / coalesced quantized gather-write.
// ---------------------------------------------------------------------------
__launch_bounds__(TPB, 4)
__global__ void fused_kernel(const float* __restrict__ vecs,
                             const float* __restrict__ mask,
                             const float* __restrict__ cb,
                             const float* __restrict__ cc,
                             const u16* __restrict__ cbh,
                             const u16* __restrict__ cbl,
                             float* __restrict__ outq,
                             float* __restrict__ outz,
                             float* __restrict__ oute,
                             float* __restrict__ partial) {
    __shared__ float4 svec[TOKS * 16];          // 32 KB, swizzled f4: g ^ (row&15)
    __shared__ u16 ldsH[QCODES * 64];           // 16 KB
    __shared__ u16 ldsL[QCODES * 64];           // 16 KB
    __shared__ u32 slots[TOKS * SLOTP];         // 6.5 KB
    __shared__ float hval[TOKS * SLOTP];        // 6.5 KB
    __shared__ u32 cnt_l[TOKS];                 // 0.5 KB
    __shared__ int z_l[TOKS];                   // 0.5 KB
    __shared__ float wsum[TPB / 64];

    const int tid = threadIdx.x;
    const int grp = blockIdx.x;      // 0..1023
    const int w = tid >> 6;          // wave 0..7
    const int lane = tid & 63;
    const int c16 = lane & 15;
    const int h = lane >> 4;

    // ---- P0a: stage vecs -> LDS (swizzled), coalesced ----
    {
        const float4* vsrc = (const float4*)(vecs + (size_t)grp * TOKS * ND);
        #pragma unroll
        for (int i = 0; i < 4; ++i) {
            int idx = i * TPB + tid;            // 2048 f4
            int row = idx >> 4, g = idx & 15;
            svec[row * 16 + (g ^ (row & 15))] = vsrc[idx];
        }
        if (tid < TOKS) cnt_l[tid] = 0;
    }
    // stage quarter 0 (1024 short8 per array / 512 threads)
    #pragma unroll
    for (int i = 0; i < 2; ++i) {
        int k = i * TPB + tid;
        ((short8*)ldsH)[k] = ((const short8*)cbh)[k];
        ((short8*)ldsL)[k] = ((const short8*)cbl)[k];
    }
    __syncthreads();

    // ---- P0b: B fragments (once). B[k][col]: col=c16 (token), k=kk*32+h*8+e ----
    const int trow = w * 16 + c16;   // this lane's token 0..127
    short8 bh[2], bl[2];
    #pragma unroll
    for (int kk = 0; kk < 2; ++kk) {
        float x[8];
        #pragma unroll
        for (int u = 0; u < 2; ++u) {
            int g = kk * 8 + h * 2 + u;
            float4 t = svec[trow * 16 + (g ^ (trow & 15))];
            x[u * 4 + 0] = t.x; x[u * 4 + 1] = t.y;
            x[u * 4 + 2] = t.z; x[u * 4 + 3] = t.w;
        }
        short8 H, L;
        #pragma unroll
        for (int e2 = 0; e2 < 8; ++e2) {
            u32 hb = f2bf_rne(x[e2]);
            float hf = __uint_as_float(hb << 16);
            u32 lb = f2bf_rne(x[e2] - hf);
            H[e2] = (short)hb; L[e2] = (short)lb;
        }
        bh[kk] = H; bl[kk] = L;
    }

    // ---- P1: quarters ----
    for (int q = 0; q < 4; ++q) {
        if (q) {
            __syncthreads();   // previous MFMA done with ldsH/L
            #pragma unroll
            for (int i = 0; i < 2; ++i) {
                int k = i * TPB + tid;
                ((short8*)ldsH)[k] = ((const short8*)(cbh + q * QCODES * 64))[k];
                ((short8*)ldsL)[k] = ((const short8*)(cbl + q * QCODES * 64))[k];
            }
            __syncthreads();
        }
        #pragma unroll
        for (int c = 0; c < 2; ++c) {             // two 64-code chunks
            f32x4 acc[4];
            #pragma unroll
            for (int mt = 0; mt < 4; ++mt) {
                int cr = q * QCODES + c * 64 + mt * 16 + h * 4;
                f32x4 ini;
                ini[0] = -0.5f * cc[cr + 0];
                ini[1] = -0.5f * cc[cr + 1];
                ini[2] = -0.5f * cc[cr + 2];
                ini[3] = -0.5f * cc[cr + 3];
                acc[mt] = ini;
            }
            #pragma unroll
            for (int mt = 0; mt < 4; ++mt) {
                int code_l = c * 64 + mt * 16 + c16;
                int sw = code_l & 7;
                short8 ah[2], al[2];
                #pragma unroll
                for (int kk = 0; kk < 2; ++kk) {
                    int off = code_l * 64 + (((kk * 4 + h) ^ sw) << 3);
                    ah[kk] = *(const short8*)(ldsH + off);
                    al[kk] = *(const short8*)(ldsL + off);
                }
                #pragma unroll
                for (int kk = 0; kk < 2; ++kk) {
                    acc[mt] = __builtin_amdgcn_mfma_f32_16x16x32_bf16(ah[kk], bh[kk], acc[mt], 0, 0, 0);
                    acc[mt] = __builtin_amdgcn_mfma_f32_16x16x32_bf16(ah[kk], bl[kk], acc[mt], 0, 0, 0);
                    acc[mt] = __builtin_amdgcn_mfma_f32_16x16x32_bf16(al[kk], bh[kk], acc[mt], 0, 0, 0);
                }
            }
            // epilogue: chunk-max per token, eps-rescan -> candidate append
            float m = acc[0][0];
            #pragma unroll
            for (int mt = 0; mt < 4; ++mt) {
                m = fmaxf(m, fmaxf(fmaxf(acc[mt][0], acc[mt][1]),
                                   fmaxf(acc[mt][2], acc[mt][3])));
            }
            m = fmaxf(m, __shfl_xor(m, 16));
            m = fmaxf(m, __shfl_xor(m, 32));
            float thr = m - EPS_H;
            #pragma unroll
            for (int mt = 0; mt < 4; ++mt) {
                #pragma unroll
                for (int r = 0; r < 4; ++r) {
                    float v = acc[mt][r];
                    if (v >= thr) {
                        u32 pos = atomicAdd(&cnt_l[trow], 1u);
                        if (pos < (u32)SLOTS) {
                            slots[trow * SLOTP + pos] = (u32)(q * QCODES + c * 64 + mt * 16 + h * 4 + r);
                            hval[trow * SLOTP + pos] = v;
                        }
                    }
                }
            }
        }
    }
    __syncthreads();

    // ---- P2: exact rescore, 4 threads/token ----
    const int p  = tid >> 2;          // token-local 0..127
    const int qs = tid & 3;
    const int tok = grp * TOKS + p;

    float4 vf[16];
    #pragma unroll
    for (int g = 0; g < 16; ++g) vf[g] = svec[p * 16 + (g ^ (p & 15))];
    float vv;
    {
        float a0 = 0.f, a1 = 0.f, a2 = 0.f, a3 = 0.f;
        #pragma unroll
        for (int i = 0; i < 16; ++i) {
            a0 = fmaf(vf[i].x, vf[i].x, a0);
            a1 = fmaf(vf[i].y, vf[i].y, a1);
            a2 = fmaf(vf[i].z, vf[i].z, a2);
            a3 = fmaf(vf[i].w, vf[i].w, a3);
        }
        vv = (a0 + a1) + (a2 + a3);
    }

    u32 cnt = cnt_l[p]; if (cnt > (u32)SLOTS) cnt = (u32)SLOTS;
    float hm = -3.4e38f;
    for (u32 j2 = 0; j2 < cnt; ++j2) hm = fmaxf(hm, hval[p * SLOTP + j2]);
    float thr2 = hm - EPS_H;

    u64 best = 0xFFFFFFFFFFFFFFFFull;
    for (u32 j2 = qs; j2 < cnt; j2 += 4) {
        if (hval[p * SLOTP + j2] >= thr2) {
            int code = (int)slots[p * SLOTP + j2];
            const float4* cs = (const float4*)(cb + (size_t)code * ND);
            float d0 = 0.f, d1 = 0.f, d2 = 0.f, d3 = 0.f;
            #pragma unroll
            for (int i2 = 0; i2 < 16; ++i2) {
                float4 cv = cs[i2];
                d0 = fmaf(cv.x, vf[i2].x, d0);
                d1 = fmaf(cv.y, vf[i2].y, d1);
                d2 = fmaf(cv.z, vf[i2].z, d2);
                d3 = fmaf(cv.w, vf[i2].w, d3);
            }
            float dot = (d0 + d1) + (d2 + d3);
            float dist = (vv - 2.0f * dot) + cc[code];
            upd_key(best, dist, code);
        }
    }
    {
        u64 o = __shfl_xor(best, 1); if (o < best) best = o;
        o = __shfl_xor(best, 2); if (o < best) best = o;
    }

    float contrib = 0.0f;
    if (qs == 0) {
        int zi = (int)(best & 0xFFFFFFFFu);
        u32 du = (u32)(best >> 32);
        du ^= (du >> 31) ? 0x80000000u : 0xFFFFFFFFu;
        float dmin = __uint_as_float(du);
        float err = fmaxf(dmin, 0.0f);
        outz[tok] = (float)zi;
        oute[tok] = err;
        z_l[p] = zi;
        contrib = mask[tok] * err;
    }
    #pragma unroll
    for (int off = 32; off > 0; off >>= 1) contrib += __shfl_xor(contrib, off);
    if (lane == 0) wsum[w] = contrib;
    __syncthreads();
    if (tid == 0) {
        float t = 0.f;
        #pragma unroll
        for (int i = 0; i < TPB / 64; ++i) t += wsum[i];
        partial[grp] = t;
    }

    // ---- P3: coalesced quantized gather-write ----
    const float4* cb4 = (const float4*)cb;
    float4* qo = (float4*)(outq + (size_t)grp * TOKS * ND);
    #pragma unroll
    for (int i = 0; i < 4; ++i) {
        int gidx = i * TPB + tid;      // 2048 f4
        int t2 = gidx >> 4;
        int sub = gidx & 15;
        qo[gidx] = cb4[(size_t)z_l[t2] * 16 + sub];
    }
}

// ---------------------------------------------------------------------------
// Kernel 3: sum 1024 partials; l_commit = sum / (B*L)
// ---------------------------------------------------------------------------
__global__ void fin_kernel(const float* __restrict__ partial, float* __restrict__ outl) {
    int t = threadIdx.x;                 // 1024
    float x = partial[t];
    #pragma unroll
    for (int off = 32; off > 0; off >>= 1) x += __shfl_xor(x, off);
    __shared__ float ws[16];
    if ((t & 63) == 0) ws[t >> 6] = x;
    __syncthreads();
    if (t == 0) {
        float s = 0.f;
        #pragma unroll
        for (int i = 0; i < 16; ++i) s += ws[i];
        outl[0] = s / (float)NTOK;
    }
}

extern "C" void kernel_launch(void* const* d_in, const int* in_sizes, int n_in,
                              void* d_out, int out_size, void* d_ws, size_t ws_size,
                              hipStream_t stream) {
    const float* vecs = (const float*)d_in[0];   // [B,1,L,D] f32
    const float* mask = (const float*)d_in[1];   // [B,L] f32

    float* out = (float*)d_out;
    float* outq = out + OFF_Q;
    float* outz = out + OFF_Z;
    float* outl = out + OFF_LC;
    float* oute = out + OFF_E;

    // ws layout (f32 offsets): cb 32768 | cc 512 | cbh 16384 | cbl 16384 | partial
    float* ws_f = (float*)d_ws;
    float* cb = ws_f;
    float* cc = ws_f + 32768;
    u16*  cbh = (u16*)(ws_f + 33280);
    u16*  cbl = (u16*)(ws_f + 49664);
    float* partial = ws_f + 66048;

    cb_kernel<<<NS, 64, 0, stream>>>(cb, cc, cbh, cbl);
    fused_kernel<<<NBLK, TPB, 0, stream>>>(vecs, mask, cb, cc, cbh, cbl,
                                           outq, outz, oute, partial);
    fin_kernel<<<1, 1024, 0, stream>>>(partial, outl);
}